// Round 4
// baseline (747.472 us; speedup 1.0000x reference)
//
#include <hip/hip_runtime.h>

#define T_STEPS 512
#define F_IN    64
#define HID     20
#define NCLS    10
#define BATCH   1024

// ---------------- helpers ----------------
__device__ __forceinline__ float sigf(float x) {
    return __builtin_amdgcn_rcpf(1.0f + __expf(-x));
}
__device__ __forceinline__ float tanh_fast(float x) {
    float e = __expf(2.0f * x);
    return 1.0f - 2.0f * __builtin_amdgcn_rcpf(e + 1.0f);
}
__device__ __forceinline__ float actf(float x, bool isG) {
    float y = isG ? 2.0f * x : x;
    float r = __builtin_amdgcn_rcpf(1.0f + __expf(-y));
    return isG ? 2.0f * r - 1.0f : r;
}
__device__ __forceinline__ float bcast(float v, int lane) {
    return __int_as_float(__builtin_amdgcn_readlane(__float_as_int(v), lane));
}

// ---------------- kernel A: Z0[B*T][80] = x @ W_ih0^T + b0 ----------------
// 128-row tile per block, staged into LDS with coalesced loads; one row/thread
// compute with wave-uniform (s_load) weights.
#define ZR 128
extern "C" __global__ __launch_bounds__(ZR)
void zgemm(const float* __restrict__ x, const float* __restrict__ W,
           const float* __restrict__ b0, float* __restrict__ Z)
{
    __shared__ float xs[ZR * 68];                 // 68-float stride (16B-aligned rows)
    const int tid = threadIdx.x;
    const size_t R0 = (size_t)blockIdx.x * ZR;

    // coalesced stage: 2048 float4s, 128 threads x 16
    #pragma unroll
    for (int i = 0; i < 16; ++i) {
        int idx = i * ZR + tid;                   // 0..2047
        int row = idx >> 4;                       // 0..127
        int c4  = idx & 15;                       // 0..15
        float4 v = *(const float4*)(x + (R0 + row) * F_IN + c4 * 4);
        *(float4*)&xs[row * 68 + c4 * 4] = v;
    }
    __syncthreads();

    float xr[F_IN];
    #pragma unroll
    for (int k = 0; k < 16; ++k)
        ((float4*)xr)[k] = *(const float4*)&xs[tid * 68 + k * 4];

    float* zr = Z + (R0 + tid) * 80;
    #pragma unroll 1
    for (int c = 0; c < 80; c += 4) {
        float a0 = b0[c], a1 = b0[c + 1], a2 = b0[c + 2], a3 = b0[c + 3];
        const float* w0 = W + c * F_IN;           // uniform -> s_load
        #pragma unroll
        for (int k = 0; k < F_IN; ++k) {
            a0 = fmaf(w0[k],            xr[k], a0);
            a1 = fmaf(w0[F_IN + k],     xr[k], a1);
            a2 = fmaf(w0[2 * F_IN + k], xr[k], a2);
            a3 = fmaf(w0[3 * F_IN + k], xr[k], a3);
        }
        *(float4*)(zr + c) = make_float4(a0, a1, a2, a3);
    }
}

// ---------------- kernel B: barrier-free recurrence, 1 wave / batch elem ----------------
// lane l: primary gate g1=l; lanes 0..15 also secondary gate g2=64+l (o[4..19]).
// gate order i[0..19] f[20..39] g[40..59] o[60..79].
extern "C" __global__ __launch_bounds__(64, 1)   // min 1 wave/EU -> no register spill
void lstm_rec(const float* __restrict__ Z0,
              const float* __restrict__ W_hh0,
              const float* __restrict__ W_ih1, const float* __restrict__ W_hh1,
              const float* __restrict__ b1,
              const float* __restrict__ W_fc, const float* __restrict__ b_fc,
              float* __restrict__ out)
{
    const int b = blockIdx.x;
    const int l = threadIdx.x;
    const int g2 = 64 + (l & 15);
    const bool isG = (l >= 40 && l < 60);

    float wh0p[HID], wh0s[HID], wi1p[HID], wi1s[HID], wh1p[HID], wh1s[HID];
    {
        const float4* p;
        p = (const float4*)(W_hh0 + l * HID);
        #pragma unroll
        for (int k = 0; k < 5; ++k) ((float4*)wh0p)[k] = p[k];
        p = (const float4*)(W_hh0 + g2 * HID);
        #pragma unroll
        for (int k = 0; k < 5; ++k) ((float4*)wh0s)[k] = p[k];
        p = (const float4*)(W_ih1 + l * HID);
        #pragma unroll
        for (int k = 0; k < 5; ++k) ((float4*)wi1p)[k] = p[k];
        p = (const float4*)(W_ih1 + g2 * HID);
        #pragma unroll
        for (int k = 0; k < 5; ++k) ((float4*)wi1s)[k] = p[k];
        p = (const float4*)(W_hh1 + l * HID);
        #pragma unroll
        for (int k = 0; k < 5; ++k) ((float4*)wh1p)[k] = p[k];
        p = (const float4*)(W_hh1 + g2 * HID);
        #pragma unroll
        for (int k = 0; k < 5; ++k) ((float4*)wh1s)[k] = p[k];
    }
    const float b1p = b1[l];
    const float b1s = b1[g2];

    const int cls = (l < NCLS) ? l : 0;
    const float* wfp = W_fc + (size_t)cls * (T_STEPS * HID);

    float c0 = 0.f, c1 = 0.f;
    float facc0 = 0.f, facc1 = 0.f, facc2 = 0.f, facc3 = 0.f;
    float sh0[HID], sh1[HID];
    #pragma unroll
    for (int j = 0; j < HID; ++j) { sh0[j] = 0.f; sh1[j] = 0.f; }

    const float* zrow = Z0 + (size_t)b * T_STEPS * 80;
    float zp0 = zrow[l],      zs0 = zrow[g2];
    float zp1 = zrow[80 + l], zs1 = zrow[80 + g2];

    for (int t = 0; t < T_STEPS; ++t) {
        float4 wf[5];
        {
            const float4* p = (const float4*)(wfp + t * HID);
            #pragma unroll
            for (int k = 0; k < 5; ++k) wf[k] = p[k];
        }
        const float zp = zp0, zs = zs0;
        zp0 = zp1; zs0 = zs1;
        if (t + 2 < T_STEPS) {
            const float* zr2 = zrow + (size_t)(t + 2) * 80;
            zp1 = zr2[l];
            zs1 = zr2[g2];
        }

        // ---- layer0 gates: 8 independent 5-deep chains ----
        float ap0 = zp, ap1 = 0.f, ap2 = 0.f, ap3 = 0.f;
        float as0 = zs, as1 = 0.f, as2 = 0.f, as3 = 0.f;
        #pragma unroll
        for (int j = 0; j < 5; ++j) {
            ap0 = fmaf(sh0[j],      wh0p[j],      ap0);
            ap1 = fmaf(sh0[5 + j],  wh0p[5 + j],  ap1);
            ap2 = fmaf(sh0[10 + j], wh0p[10 + j], ap2);
            ap3 = fmaf(sh0[15 + j], wh0p[15 + j], ap3);
            as0 = fmaf(sh0[j],      wh0s[j],      as0);
            as1 = fmaf(sh0[5 + j],  wh0s[5 + j],  as1);
            as2 = fmaf(sh0[10 + j], wh0s[10 + j], as2);
            as3 = fmaf(sh0[15 + j], wh0s[15 + j], as3);
        }
        // ---- layer1 h1-part (independent -> overlaps activation latency) ----
        float bp0 = b1p, bp1 = 0.f, bp2 = 0.f, bp3 = 0.f;
        float bs0 = b1s, bs1 = 0.f, bs2 = 0.f, bs3 = 0.f;
        #pragma unroll
        for (int j = 0; j < 5; ++j) {
            bp0 = fmaf(sh1[j],      wh1p[j],      bp0);
            bp1 = fmaf(sh1[5 + j],  wh1p[5 + j],  bp1);
            bp2 = fmaf(sh1[10 + j], wh1p[10 + j], bp2);
            bp3 = fmaf(sh1[15 + j], wh1p[15 + j], bp3);
            bs0 = fmaf(sh1[j],      wh1s[j],      bs0);
            bs1 = fmaf(sh1[5 + j],  wh1s[5 + j],  bs1);
            bs2 = fmaf(sh1[10 + j], wh1s[10 + j], bs2);
            bs3 = fmaf(sh1[15 + j], wh1s[15 + j], bs3);
        }
        const float a_p = (ap0 + ap1) + (ap2 + ap3);
        const float a_s = (as0 + as1) + (as2 + as3);
        const float actP = actf(a_p, isG);
        const float actS = sigf(a_s);

        // ---- layer0 state update (meaningful on lanes 0..19) ----
        {
            float fv = __shfl(actP, l + 20);
            float gv = __shfl(actP, l + 40);
            float oA = __shfl(actP, l + 60);
            float oB = __shfl(actS, l - 4);
            float ov = (l < 4) ? oA : oB;
            c0 = fmaf(fv, c0, actP * gv);
            float h0v = ov * tanh_fast(c0);
            #pragma unroll
            for (int j = 0; j < HID; ++j) sh0[j] = bcast(h0v, j);
        }

        // ---- layer1 h0-part + activation ----
        #pragma unroll
        for (int j = 0; j < 5; ++j) {
            bp0 = fmaf(sh0[j],      wi1p[j],      bp0);
            bp1 = fmaf(sh0[5 + j],  wi1p[5 + j],  bp1);
            bp2 = fmaf(sh0[10 + j], wi1p[10 + j], bp2);
            bp3 = fmaf(sh0[15 + j], wi1p[15 + j], bp3);
            bs0 = fmaf(sh0[j],      wi1s[j],      bs0);
            bs1 = fmaf(sh0[5 + j],  wi1s[5 + j],  bs1);
            bs2 = fmaf(sh0[10 + j], wi1s[10 + j], bs2);
            bs3 = fmaf(sh0[15 + j], wi1s[15 + j], bs3);
        }
        const float b_p = (bp0 + bp1) + (bp2 + bp3);
        const float b_s = (bs0 + bs1) + (bs2 + bs3);
        const float actP1 = actf(b_p, isG);
        const float actS1 = sigf(b_s);

        // ---- layer1 state update ----
        {
            float fv = __shfl(actP1, l + 20);
            float gv = __shfl(actP1, l + 40);
            float oA = __shfl(actP1, l + 60);
            float oB = __shfl(actS1, l - 4);
            float ov = (l < 4) ? oA : oB;
            c1 = fmaf(fv, c1, actP1 * gv);
            float h1v = ov * tanh_fast(c1);
            #pragma unroll
            for (int j = 0; j < HID; ++j) sh1[j] = bcast(h1v, j);
        }

        // ---- FC accumulation (4 persistent chains) ----
        {
            const float* wfs = (const float*)wf;
            #pragma unroll
            for (int j = 0; j < 5; ++j) {
                facc0 = fmaf(sh1[j],      wfs[j],      facc0);
                facc1 = fmaf(sh1[5 + j],  wfs[5 + j],  facc1);
                facc2 = fmaf(sh1[10 + j], wfs[10 + j], facc2);
                facc3 = fmaf(sh1[15 + j], wfs[15 + j], facc3);
            }
        }
    }

    if (l < NCLS)
        out[(size_t)b * NCLS + l] = ((facc0 + facc1) + (facc2 + facc3)) + b_fc[l];
}

extern "C" void kernel_launch(void* const* d_in, const int* in_sizes, int n_in,
                              void* d_out, int out_size, void* d_ws, size_t ws_size,
                              hipStream_t stream) {
    const float* x     = (const float*)d_in[0];
    const float* W_ih0 = (const float*)d_in[1];
    const float* W_hh0 = (const float*)d_in[2];
    const float* b0    = (const float*)d_in[3];
    const float* W_ih1 = (const float*)d_in[4];
    const float* W_hh1 = (const float*)d_in[5];
    const float* b1    = (const float*)d_in[6];
    const float* W_fc  = (const float*)d_in[7];
    const float* b_fc  = (const float*)d_in[8];
    float* out = (float*)d_out;

    float* Z0 = (float*)d_ws;   // B*T*80*4 = 167.8 MB of workspace

    const int rows = BATCH * T_STEPS;                    // 524288
    zgemm<<<dim3(rows / ZR), dim3(ZR), 0, stream>>>(x, W_ih0, b0, Z0);
    lstm_rec<<<dim3(BATCH), dim3(64), 0, stream>>>(Z0, W_hh0, W_ih1, W_hh1,
                                                   b1, W_fc, b_fc, out);
}